// Round 1
// 8729.736 us; speedup vs baseline: 1.3810x; 1.3810x over previous
//
#include <hip/hip_runtime.h>
#include <hip/hip_cooperative_groups.h>

namespace cg = cooperative_groups;

typedef unsigned short u16;
typedef __attribute__((ext_vector_type(8))) short bf16x8;
typedef __attribute__((ext_vector_type(4))) float f32x4;

#define NB 128
#define NOBJ 36
#define VDIM 2048
#define EMB 1024
#define HID 1024
#define NTOK 10000
#define MAXLEN 20
#define T_STEPS 19
#define PRED_STRIDE (MAXLEN * NTOK)          /* 200000 */
#define ALPHA_OFF ((long)NB * MAXLEN * NTOK) /* 25,600,000 */
#define HSZ (NB * HID)                       /* 131072 */

struct Args {
  const float *v, *caption;
  const int *cap_len;
  const float *Wih1, *Whh1, *bih1, *bhh1, *Wih2, *Whh2, *bih2, *bhh2;
  const float *Wv, *bv, *Wq, *bq, *wa, *ba, *W1, *b1, *W2, *b2;
  float *out;
  int *order, *dl;
  // bf16 conversions (built in P0 every launch)
  u16 *Wih1h, *Whh1h, *Wih2h, *Whh2h, *Wvh, *W2h, *vh, *caph, *capl;
  // fold inputs/outputs
  u16 *Wqh, *Wql, *W1T, *Wih2hql, *Wq1u, *Wih2qu;
  u16 *vproj16;
  float *gv1, *gh2s, *h1f, *h2f, *qf, *gcap, *g1a, *g1c, *g2a, *g2b, *gi2h1;
  float *bq1f, *bf2f;
  u16 *h1hi, *h1lo, *h2hi, *h2lo, *avhi, *avlo, *vmhi, *vmlo;
};

__device__ inline float b2f(u16 h) {
  unsigned u = ((unsigned)h) << 16;
  float f;
  __builtin_memcpy(&f, &u, 4);
  return f;
}
__device__ inline u16 f2b_trunc(float x) {
  unsigned u;
  __builtin_memcpy(&u, &x, 4);
  return (u16)(u >> 16);
}
__device__ inline u16 f2b_rne(float x) {
  unsigned u;
  __builtin_memcpy(&u, &x, 4);
  unsigned r = (u + 0x7fffu + ((u >> 16) & 1u)) >> 16;
  return (u16)r;
}
__device__ inline void split_bf16(float x, u16 &hi, u16 &lo) {
  hi = f2b_trunc(x);
  lo = f2b_trunc(x - b2f(hi));
}
__device__ inline bf16x8 ldb8(const u16 *p) {
  uint4 u = *(const uint4 *)p;
  bf16x8 v;
  __builtin_memcpy(&v, &u, 16);
  return v;
}
__device__ inline f32x4 mfma16(bf16x8 a, bf16x8 b, f32x4 c) {
  return __builtin_amdgcn_mfma_f32_16x16x32_bf16(a, b, c, 0, 0, 0);
}
__device__ inline float sigmoidf_(float x) {
  float e = __expf(-fabsf(x));
  float p = 1.f / (1.f + e);
  return x >= 0.f ? p : 1.f - p;
}
__device__ inline float tanhf_(float x) {
  float e = __expf(-2.f * fabsf(x));
  float t = (1.f - e) / (1.f + e);
  return x >= 0.f ? t : -t;
}
__device__ inline float wred_sum(float x) {
#pragma unroll
  for (int off = 32; off > 0; off >>= 1) x += __shfl_xor(x, off, 64);
  return x;
}
__device__ inline float wred_max(float x) {
#pragma unroll
  for (int off = 32; off > 0; off >>= 1) x = fmaxf(x, __shfl_xor(x, off, 64));
  return x;
}

// f32 -> bf16(RNE), grid-strided, float4/ushort4 vectorized (n % 4 == 0)
__device__ inline void cvt_hi(const float *src, u16 *dst, long n, long g0,
                              long gs) {
  for (long i = g0 * 4; i < n; i += gs * 4) {
    float4 f = *(const float4 *)(src + i);
    ushort4 o;
    o.x = f2b_rne(f.x);
    o.y = f2b_rne(f.y);
    o.z = f2b_rne(f.z);
    o.w = f2b_rne(f.w);
    *(ushort4 *)(dst + i) = o;
  }
}
// f32 -> hi(trunc) + lo(residual) split
__device__ inline void cvt_split(const float *src, u16 *dhi, u16 *dlo, long n,
                                 long g0, long gs) {
  for (long i = g0 * 4; i < n; i += gs * 4) {
    float4 f = *(const float4 *)(src + i);
    ushort4 h, l;
    split_bf16(f.x, h.x, l.x);
    split_bf16(f.y, h.y, l.y);
    split_bf16(f.z, h.z, l.z);
    split_bf16(f.w, h.w, l.w);
    *(ushort4 *)(dhi + i) = h;
    *(ushort4 *)(dlo + i) = l;
  }
}

// Per-wave K-loop: acc[i] += X(hi[+lo]) @ W-rows(i-th tile, stride wstride).
// A-frag: lane holds A[m=lane&15][k=quad*8+j]; B-frag: W[n=lane&15][same k].
#define MMK_BODY                                                               \
  {                                                                            \
    const int ko = ks * 32;                                                    \
    bf16x8 va = ldb8(ah + ko);                                                 \
    bf16x8 vl;                                                                 \
    if constexpr (SPLIT) vl = ldb8(al + ko);                                   \
    _Pragma("unroll") for (int i = 0; i < NT; ++i) {                           \
      bf16x8 vb = ldb8(wr + (long)i * wstride + ko);                           \
      acc[i] = mfma16(va, vb, acc[i]);                                         \
      if constexpr (SPLIT) acc[i] = mfma16(vl, vb, acc[i]);                    \
    }                                                                          \
  }

template <int NT, bool SPLIT>
__device__ inline void mmk(f32x4 *acc, const u16 *ah, const u16 *al,
                           const u16 *wr, long wstride, int ksteps) {
  if constexpr (NT == 1) {
#pragma unroll 4
    for (int ks = 0; ks < ksteps; ++ks) MMK_BODY
  } else {
#pragma unroll 2
    for (int ks = 0; ks < ksteps; ++ks) MMK_BODY
  }
}

// single 128x16 output tile, NT=1 (per-lane pointers precomputed by caller)
template <bool SPLIT>
__device__ inline f32x4 tile16(const u16 *ah, const u16 *al, const u16 *wr,
                               int K) {
  f32x4 acc = {0.f, 0.f, 0.f, 0.f};
  mmk<1, SPLIT>(&acc, ah, al, wr, 0, K >> 5);
  return acc;
}

__global__ void __launch_bounds__(512, 4) butd(Args a) {
  cg::grid_group grid = cg::this_grid();
  const int tid = threadIdx.x;
  const int blk = blockIdx.x;
  const int gx = gridDim.x;
  const int lane = tid & 63;
  const int wv = tid >> 6; // 0..7
  const int m = lane & 15;
  const int quad = lane >> 4;
  __shared__ float sl[64];

  const long gs = (long)gx * 512;
  const long g0 = (long)blk * 512 + tid;

  //================= P0: conversions + argsort + zero-init ==================
  cvt_hi(a.Wih1, a.Wih1h, 3072L * 4096, g0, gs);
  cvt_hi(a.Whh1, a.Whh1h, 3072L * 1024, g0, gs);
  cvt_hi(a.Wih2, a.Wih2h, 3072L * 3072, g0, gs);
  cvt_hi(a.Whh2, a.Whh2h, 3072L * 1024, g0, gs);
  cvt_hi(a.Wv, a.Wvh, 1024L * 2048, g0, gs);
  cvt_hi(a.W2, a.W2h, (long)NTOK * 1024, g0, gs);
  cvt_hi(a.v, a.vh, (long)NB * NOBJ * VDIM, g0, gs);
  cvt_split(a.caption, a.caph, a.capl, (long)NB * MAXLEN * EMB, g0, gs);
  cvt_split(a.Wq, a.Wqh, a.Wql, 1024L * 1024, g0, gs); // fold A-side
  // W1T[i][m] = bf16_rne(W1[m][i])  (fold B-side)
  for (long i = g0; i < 1024L * 1024; i += gs) {
    const int ii = (int)(i >> 10), mm2 = (int)(i & 1023);
    a.W1T[i] = f2b_rne(a.W1[(long)mm2 * 1024 + ii]);
  }
  // lo-residual of Wih2[:, 2048:3072] w.r.t. its RNE hi (stored in Wih2h)
  for (long i = g0 * 4; i < 3072L * 1024; i += gs * 4) {
    const int row = (int)(i >> 10), c = (int)(i & 1023);
    float4 f = *(const float4 *)(a.Wih2 + (long)row * 3072 + 2048 + c);
    ushort4 l;
    l.x = f2b_trunc(f.x - b2f(f2b_rne(f.x)));
    l.y = f2b_trunc(f.y - b2f(f2b_rne(f.y)));
    l.z = f2b_trunc(f.z - b2f(f2b_rne(f.z)));
    l.w = f2b_trunc(f.w - b2f(f2b_rne(f.w)));
    *(ushort4 *)(a.Wih2hql + i) = l;
  }

  if (blk == 0 && tid < NB) {
    int ki = a.cap_len[tid];
    int rank = 0;
    for (int j = 0; j < NB; ++j) {
      int kj = a.cap_len[j];
      rank += (kj > ki) || (kj == ki && j < tid);
    }
    a.order[rank] = tid;
    a.dl[rank] = ki - 1;
  }
  for (long i = g0; i < (long)NB * NTOK; i += gs) {
    long b = i / NTOK, n = i - b * NTOK;
    a.out[b * PRED_STRIDE + (long)(MAXLEN - 1) * NTOK + n] = 0.f;
  }
  for (long i = g0; i < (long)NB * NOBJ; i += gs) {
    long b = i / NOBJ, n = i - b * NOBJ;
    a.out[ALPHA_OFF + b * (MAXLEN * NOBJ) + (MAXLEN - 1) * NOBJ + n] = 0.f;
  }
  for (long i = g0; i < HSZ; i += gs) { // zero parity-0 state buffers
    a.h1f[i] = 0.f;
    a.h2f[i] = 0.f;
    a.h1hi[i] = 0;
    a.h1lo[i] = 0;
    a.h2hi[i] = 0;
    a.h2lo[i] = 0;
  }
  for (long i = g0; i < 128L * 3072; i += gs) a.g1c[i] = 0.f; // gh1 at t=0
  grid.sync();

  //================= P1: v_mean + vproj GEMM + bias folds ===================
  for (int b = blk; b < NB; b += gx) {
    const int ob = a.order[b];
    const float *vb = a.v + (long)ob * NOBJ * VDIM;
    for (int d = tid; d < VDIM; d += 512) {
      float s = 0.f;
      for (int k = 0; k < NOBJ; ++k) s += vb[(long)k * VDIM + d];
      s *= (1.f / 36.f);
      u16 hi, lo;
      split_bf16(s, hi, lo);
      a.vmhi[b * VDIM + d] = hi;
      a.vmlo[b * VDIM + d] = lo;
    }
  }
  // vproj[b,k,:] = relu(v@Wv^T + bv): 576 tasks of 128 rows x 64 cols
  for (int tt = blk; tt < 576; tt += gx) {
    const int mg = tt % 36, ngr = tt / 36;
    const int row = mg * 128 + wv * 16 + m;
    const int bb = row / NOBJ, ko = row - bb * NOBJ;
    const u16 *ar = a.vh + ((long)a.order[bb] * NOBJ + ko) * VDIM + quad * 8;
    const int c0 = ngr * 64;
    const u16 *wr = a.Wvh + (long)(c0 + m) * VDIM + quad * 8;
    f32x4 acc[4] = {};
    mmk<4, false>(acc, ar, nullptr, wr, 16L * VDIM, VDIM / 32);
#pragma unroll
    for (int i = 0; i < 4; ++i) {
      const int col = c0 + i * 16 + m;
      const float bvv = a.bv[col];
#pragma unroll
      for (int r = 0; r < 4; ++r) {
        const int grow = mg * 128 + wv * 16 + quad * 4 + r;
        a.vproj16[(long)grow * HID + col] = f2b_rne(fmaxf(acc[i][r] + bvv, 0.f));
      }
    }
  }
  // bias folds: bq1 = Wq@b1 + bq ; bf2 = Wih2[:,2048:3072]@b1
  for (int o = blk * 8 + wv; o < 4096; o += gx * 8) {
    if (o < 1024) {
      float s = 0.f;
      for (int c = lane; c < 1024; c += 64) s += a.Wq[(long)o * 1024 + c] * a.b1[c];
      s = wred_sum(s);
      if (lane == 0) a.bq1f[o] = s + a.bq[o];
    } else {
      const int oo = o - 1024;
      float s = 0.f;
      for (int c = lane; c < 1024; c += 64)
        s += a.Wih2[(long)oo * 3072 + 2048 + c] * a.b1[c];
      s = wred_sum(s);
      if (lane == 0) a.bf2f[oo] = s;
    }
  }
  grid.sync();

  //== P2: gv1, GCAP (caption GEMM hoisted over all t), fold GEMMs ===========
  // pool: [0,192) gv1 | [192,3840) gcap | [3840,4352) Wq1 | [4352,5888) Wih2q
  {
    const int arow = wv * 16 + m;
    for (int task = blk; task < 5888; task += gx) {
      if (task < 192) { // gv1 = v_mean @ Wih1[:,1024:3072]^T + bih1
        const int col = task * 16 + m;
        f32x4 acc = tile16<true>(
            a.vmhi + (long)arow * VDIM + quad * 8,
            a.vmlo + (long)arow * VDIM + quad * 8,
            a.Wih1h + (long)col * 4096 + 1024 + quad * 8, VDIM);
        const float bb = a.bih1[col];
#pragma unroll
        for (int r = 0; r < 4; ++r)
          a.gv1[(long)(wv * 16 + quad * 4 + r) * 3072 + col] = acc[r] + bb;
      } else if (task < 3840) { // gcap[t] = caption_t @ Wih1[:,3072:4096]^T
        const int tt2 = task - 192;
        const int tdx = tt2 / 192, ct = tt2 % 192;
        const int col = ct * 16 + m;
        const long capoff = ((long)a.order[arow] * MAXLEN + tdx) * EMB;
        f32x4 acc = tile16<true>(
            a.caph + capoff + quad * 8, a.capl + capoff + quad * 8,
            a.Wih1h + (long)col * 4096 + 3072 + quad * 8, EMB);
#pragma unroll
        for (int r = 0; r < 4; ++r)
          a.gcap[((long)tdx * NB + wv * 16 + quad * 4 + r) * 3072 + col] =
              acc[r];
      } else if (task < 4352) { // Wq1 = Wq @ W1  (split-A x hi-B)
        const int tt2 = task - 3840;
        const int rg = tt2 >> 6, ct = tt2 & 63;
        const int row = rg * 128 + arow, col = ct * 16 + m;
        f32x4 acc = tile16<true>(a.Wqh + (long)row * HID + quad * 8,
                                 a.Wql + (long)row * HID + quad * 8,
                                 a.W1T + (long)col * HID + quad * 8, HID);
#pragma unroll
        for (int r = 0; r < 4; ++r) {
          const int o = rg * 128 + wv * 16 + quad * 4 + r;
          a.Wq1u[(long)o * HID + col] = f2b_rne(acc[r]);
        }
      } else { // Wih2q = Wih2[:,2048:3072] @ W1
        const int tt2 = task - 4352;
        const int rg = tt2 >> 6, ct = tt2 & 63;
        const int row = rg * 128 + arow, col = ct * 16 + m;
        f32x4 acc = tile16<true>(
            a.Wih2h + (long)row * 3072 + 2048 + quad * 8,
            a.Wih2hql + (long)row * HID + quad * 8,
            a.W1T + (long)col * HID + quad * 8, HID);
#pragma unroll
        for (int r = 0; r < 4; ++r) {
          const int o = rg * 128 + wv * 16 + quad * 4 + r;
          a.Wih2qu[(long)o * HID + col] = f2b_rne(acc[r]);
        }
      }
    }
  }
  grid.sync();

  //================= steady-state per-step lambdas ==========================
  const int arow = wv * 16 + m;

  auto word_tile = [&](int wt, int tf, int pb) { // 16 cols of W2 per tile
    const int col = wt * 16 + m;
    f32x4 acc = tile16<true>(
        a.h2hi + (long)pb * HSZ + (long)arow * HID + quad * 8,
        a.h2lo + (long)pb * HSZ + (long)arow * HID + quad * 8,
        a.W2h + (long)col * HID + quad * 8, HID);
    const float bb = a.b2[col];
#pragma unroll
    for (int r = 0; r < 4; ++r) {
      const int grow = wv * 16 + quad * 4 + r;
      const int msk = tf < a.dl[grow];
      a.out[(long)grow * PRED_STRIDE + (long)tf * NTOK + col] =
          msk ? acc[r] + bb : 0.f;
    }
  };

  auto attention = [&](int t, int b, int half) {
    __syncthreads();
    const int ob = a.order[b];
    const float *qrow = a.qf + (long)b * HID;
    for (int k = wv; k < NOBJ; k += 8) {
      const u16 *vp = a.vproj16 + ((long)b * NOBJ + k) * HID;
      float s = 0.f;
      for (int d = lane; d < HID; d += 64) s += b2f(vp[d]) * qrow[d] * a.wa[d];
      s = wred_sum(s);
      if (lane == 0) sl[k] = s + a.ba[0];
    }
    __syncthreads();
    if (wv == 0) {
      float x = (lane < NOBJ) ? sl[lane] : -3.0e38f;
      float mx = wred_max(x);
      float e = (lane < NOBJ) ? __expf(x - mx) : 0.f;
      float den = wred_sum(e);
      float att = e / den;
      if (lane < NOBJ) {
        sl[lane] = att;
        if (half == 0) {
          const int msk = t < a.dl[b];
          a.out[ALPHA_OFF + (long)b * (MAXLEN * NOBJ) + t * NOBJ + lane] =
              msk ? att : 0.f;
        }
      }
    }
    __syncthreads();
    const u16 *vb = a.vh + (long)ob * NOBJ * VDIM + half * 1024;
    for (int d = tid; d < 1024; d += 512) {
      float s = 0.f;
#pragma unroll
      for (int k = 0; k < NOBJ; ++k) s += sl[k] * b2f(vb[(long)k * VDIM + d]);
      u16 hi, lo;
      split_bf16(s, hi, lo);
      a.avhi[(long)b * VDIM + half * 1024 + d] = hi;
      a.avlo[(long)b * VDIM + half * 1024 + d] = lo;
    }
  };

  // S1: g1a = h2@Wih1[:, :1024]^T | gh2s = h2@Whh2^T + bhh2 | word(t-1) 0..127
  auto S1 = [&](int t) {
    const int pr = t & 1;
    const u16 *h2h = a.h2hi + (long)pr * HSZ + (long)arow * HID + quad * 8;
    const u16 *h2l = a.h2lo + (long)pr * HSZ + (long)arow * HID + quad * 8;
    for (int task = blk; task < 512; task += gx) {
      if (task < 192) {
        const int col = task * 16 + m;
        f32x4 acc = tile16<true>(h2h, h2l,
                                 a.Wih1h + (long)col * 4096 + quad * 8, HID);
#pragma unroll
        for (int r = 0; r < 4; ++r)
          a.g1a[(long)(wv * 16 + quad * 4 + r) * 3072 + col] = acc[r];
      } else if (task < 384) {
        const int col = (task - 192) * 16 + m;
        f32x4 acc =
            tile16<true>(h2h, h2l, a.Whh2h + (long)col * HID + quad * 8, HID);
        const float bb = a.bhh2[col];
#pragma unroll
        for (int r = 0; r < 4; ++r)
          a.gh2s[(long)(wv * 16 + quad * 4 + r) * 3072 + col] = acc[r] + bb;
      } else if (t > 0) {
        word_tile(task - 384, t - 1, pr);
      }
    }
  };

  // S2: GRU1 pointwise -> h1n ; word(t-1) tiles 128..383
  auto S2 = [&](int t) {
    const int pr = t & 1, pw_ = pr ^ 1;
    for (long i = g0; i < (long)HSZ; i += gs) {
      const int row = (int)(i >> 10), col = (int)(i & 1023);
      const long o3 = (long)row * 3072 + col;
      const float *gc = a.gcap + ((long)t * NB + row) * 3072 + col;
      float ir = a.g1a[o3] + gc[0] + a.gv1[o3];
      float iz = a.g1a[o3 + 1024] + gc[1024] + a.gv1[o3 + 1024];
      float in_ = a.g1a[o3 + 2048] + gc[2048] + a.gv1[o3 + 2048];
      float hr = a.g1c[o3] + a.bhh1[col];
      float hz = a.g1c[o3 + 1024] + a.bhh1[HID + col];
      float hn = a.g1c[o3 + 2048] + a.bhh1[2 * HID + col];
      float rr = sigmoidf_(ir + hr);
      float zz = sigmoidf_(iz + hz);
      float nn = tanhf_(in_ + rr * hn);
      const long io = (long)pr * HSZ + i, iw = (long)pw_ * HSZ + i;
      float hnew = (1.f - zz) * nn + zz * a.h1f[io];
      a.h1f[iw] = hnew;
      u16 hi, lo;
      split_bf16(hnew, hi, lo);
      a.h1hi[iw] = hi;
      a.h1lo[iw] = lo;
    }
    if (t > 0)
      for (int task = blk; task < 256; task += gx)
        word_tile(128 + task, t - 1, t & 1);
  };

  // S3: q = relu(h1n@Wq1^T + bq1) | gi2h1 = h1n@Wih2q^T | word 384..624
  auto S3 = [&](int t) {
    const int pw_ = (t & 1) ^ 1;
    const u16 *h1h = a.h1hi + (long)pw_ * HSZ + (long)arow * HID + quad * 8;
    const u16 *h1l = a.h1lo + (long)pw_ * HSZ + (long)arow * HID + quad * 8;
    for (int task = blk; task < 497; task += gx) {
      if (task < 64) {
        const int col = task * 16 + m;
        f32x4 acc =
            tile16<true>(h1h, h1l, a.Wq1u + (long)col * HID + quad * 8, HID);
        const float bb = a.bq1f[col];
#pragma unroll
        for (int r = 0; r < 4; ++r)
          a.qf[(long)(wv * 16 + quad * 4 + r) * HID + col] =
              fmaxf(acc[r] + bb, 0.f);
      } else if (task < 256) {
        const int col = (task - 64) * 16 + m;
        f32x4 acc =
            tile16<true>(h1h, h1l, a.Wih2qu + (long)col * HID + quad * 8, HID);
#pragma unroll
        for (int r = 0; r < 4; ++r)
          a.gi2h1[(long)(wv * 16 + quad * 4 + r) * 3072 + col] = acc[r];
      } else if (t > 0) {
        word_tile(384 + (task - 256), t - 1, t & 1);
      }
    }
  };

  // S4: attention (2-way d-split) | g1c = h1n@Whh1^T for step t+1
  auto S4 = [&](int t) {
    const int pw_ = (t & 1) ^ 1;
    for (int task = blk; task < 448; task += gx) {
      if (task < 256) {
        attention(t, task & 127, task >> 7);
      } else if (t + 1 < T_STEPS) {
        const int col = (task - 256) * 16 + m;
        f32x4 acc = tile16<true>(
            a.h1hi + (long)pw_ * HSZ + (long)arow * HID + quad * 8,
            a.h1lo + (long)pw_ * HSZ + (long)arow * HID + quad * 8,
            a.Whh1h + (long)col * HID + quad * 8, HID);
#pragma unroll
        for (int r = 0; r < 4; ++r)
          a.g1c[(long)(wv * 16 + quad * 4 + r) * 3072 + col] = acc[r];
      }
    }
  };

  // S5: g2a/g2b = att_v @ Wih2[:, :2048]^T  (K split in halves)
  auto S5 = [&](int t) {
    (void)t;
    for (int task = blk; task < 384; task += gx) {
      const int kh = task / 192, ct = task % 192;
      const int col = ct * 16 + m;
      f32x4 acc = tile16<true>(
          a.avhi + kh * 1024 + (long)arow * VDIM + quad * 8,
          a.avlo + kh * 1024 + (long)arow * VDIM + quad * 8,
          a.Wih2h + (long)col * 3072 + kh * 1024 + quad * 8, HID);
      float *dst = kh ? a.g2b : a.g2a;
#pragma unroll
      for (int r = 0; r < 4; ++r)
        dst[(long)(wv * 16 + quad * 4 + r) * 3072 + col] = acc[r];
    }
  };

  // S6: GRU2 pointwise -> h2n
  auto S6 = [&](int t) {
    const int pr = t & 1, pw_ = pr ^ 1;
    for (long i = g0; i < (long)HSZ; i += gs) {
      const int row = (int)(i >> 10), col = (int)(i & 1023);
      const long o3 = (long)row * 3072 + col;
      float ir = a.g2a[o3] + a.g2b[o3] + a.gi2h1[o3] + a.bih2[col] + a.bf2f[col];
      float iz = a.g2a[o3 + 1024] + a.g2b[o3 + 1024] + a.gi2h1[o3 + 1024] +
                 a.bih2[HID + col] + a.bf2f[HID + col];
      float in_ = a.g2a[o3 + 2048] + a.g2b[o3 + 2048] + a.gi2h1[o3 + 2048] +
                  a.bih2[2 * HID + col] + a.bf2f[2 * HID + col];
      float hr = a.gh2s[o3], hz = a.gh2s[o3 + 1024], hn = a.gh2s[o3 + 2048];
      float rr = sigmoidf_(ir + hr);
      float zz = sigmoidf_(iz + hz);
      float nn = tanhf_(in_ + rr * hn);
      const long io = (long)pr * HSZ + i, iw = (long)pw_ * HSZ + i;
      float hnew = (1.f - zz) * nn + zz * a.h2f[io];
      a.h2f[iw] = hnew;
      u16 hi, lo;
      split_bf16(hnew, hi, lo);
      a.h2hi[iw] = hi;
      a.h2lo[iw] = lo;
    }
  };

  for (int t = 0; t < T_STEPS; ++t) {
    S1(t);
    grid.sync();
    S2(t);
    grid.sync();
    S3(t);
    grid.sync();
    S4(t);
    grid.sync();
    S5(t);
    grid.sync();
    S6(t);
    grid.sync();
  }
  // final word(T-1): h2(18) lives in parity 1
  for (int wt = blk; wt < 625; wt += gx) word_tile(wt, T_STEPS - 1, T_STEPS & 1);
}

extern "C" void kernel_launch(void *const *d_in, const int *in_sizes, int n_in,
                              void *d_out, int out_size, void *d_ws,
                              size_t ws_size, hipStream_t stream) {
  Args a;
  a.v = (const float *)d_in[0];
  a.caption = (const float *)d_in[1];
  a.cap_len = (const int *)d_in[2];
  a.Wih1 = (const float *)d_in[3];
  a.Whh1 = (const float *)d_in[4];
  a.bih1 = (const float *)d_in[5];
  a.bhh1 = (const float *)d_in[6];
  a.Wih2 = (const float *)d_in[7];
  a.Whh2 = (const float *)d_in[8];
  a.bih2 = (const float *)d_in[9];
  a.bhh2 = (const float *)d_in[10];
  a.Wv = (const float *)d_in[11];
  a.bv = (const float *)d_in[12];
  a.Wq = (const float *)d_in[13];
  a.bq = (const float *)d_in[14];
  a.wa = (const float *)d_in[15];
  a.ba = (const float *)d_in[16];
  a.W1 = (const float *)d_in[17];
  a.b1 = (const float *)d_in[18];
  a.W2 = (const float *)d_in[19];
  a.b2 = (const float *)d_in[20];
  a.out = (float *)d_out;

  char *w = (char *)d_ws;
  size_t off = 0;
  auto take = [&](size_t bytes) -> void * {
    void *p = w + off;
    off += (bytes + 255) & ~(size_t)255;
    return p;
  };
  a.order = (int *)take(NB * 4);
  a.dl = (int *)take(NB * 4);
  a.Wih1h = (u16 *)take(3072UL * 4096 * 2);
  a.Whh1h = (u16 *)take(3072UL * 1024 * 2);
  a.Wih2h = (u16 *)take(3072UL * 3072 * 2);
  a.Whh2h = (u16 *)take(3072UL * 1024 * 2);
  a.Wvh = (u16 *)take(1024UL * 2048 * 2);
  a.W2h = (u16 *)take((size_t)NTOK * 1024 * 2);
  a.vh = (u16 *)take((size_t)NB * NOBJ * VDIM * 2);
  a.caph = (u16 *)take((size_t)NB * MAXLEN * EMB * 2);
  a.capl = (u16 *)take((size_t)NB * MAXLEN * EMB * 2);
  a.Wqh = (u16 *)take(1024UL * 1024 * 2);
  a.Wql = (u16 *)take(1024UL * 1024 * 2);
  a.W1T = (u16 *)take(1024UL * 1024 * 2);
  a.Wih2hql = (u16 *)take(3072UL * 1024 * 2);
  a.Wq1u = (u16 *)take(1024UL * 1024 * 2);
  a.Wih2qu = (u16 *)take(3072UL * 1024 * 2);
  a.vproj16 = (u16 *)take((size_t)NB * NOBJ * HID * 2);
  a.gv1 = (float *)take((size_t)NB * 3072 * 4);
  a.gh2s = (float *)take((size_t)NB * 3072 * 4);
  a.h1f = (float *)take((size_t)2 * HSZ * 4);
  a.h2f = (float *)take((size_t)2 * HSZ * 4);
  a.qf = (float *)take((size_t)HSZ * 4);
  a.gcap = (float *)take((size_t)T_STEPS * NB * 3072 * 4);
  a.g1a = (float *)take((size_t)NB * 3072 * 4);
  a.g1c = (float *)take((size_t)NB * 3072 * 4);
  a.g2a = (float *)take((size_t)NB * 3072 * 4);
  a.g2b = (float *)take((size_t)NB * 3072 * 4);
  a.gi2h1 = (float *)take((size_t)NB * 3072 * 4);
  a.bq1f = (float *)take(1024UL * 4);
  a.bf2f = (float *)take(3072UL * 4);
  a.h1hi = (u16 *)take((size_t)2 * HSZ * 2);
  a.h1lo = (u16 *)take((size_t)2 * HSZ * 2);
  a.h2hi = (u16 *)take((size_t)2 * HSZ * 2);
  a.h2lo = (u16 *)take((size_t)2 * HSZ * 2);
  a.avhi = (u16 *)take((size_t)NB * VDIM * 2);
  a.avlo = (u16 *)take((size_t)NB * VDIM * 2);
  a.vmhi = (u16 *)take((size_t)NB * VDIM * 2);
  a.vmlo = (u16 *)take((size_t)NB * VDIM * 2);

  static int gridBlocks = 0;
  if (gridBlocks == 0) {
    int occ = 0;
    if (hipOccupancyMaxActiveBlocksPerMultiprocessor(&occ, (const void *)butd,
                                                     512, 0) != hipSuccess ||
        occ < 1)
      occ = 1;
    gridBlocks = (occ >= 2) ? 512 : 256;
  }

  void *kargs[] = {(void *)&a};
  hipLaunchCooperativeKernel((const void *)butd, dim3(gridBlocks), dim3(512),
                             kargs, 0, stream);
}